// Round 1
// baseline (1063.724 us; speedup 1.0000x reference)
//
#include <hip/hip_runtime.h>
#include <hip/hip_bf16.h>
#include <stdint.h>

#define U_NODES 50000
#define I_NODES 20000
#define N_NODES 70000
#define M_PAD   70016      // 547 * 128
#define E_EDGES 400000
#define HID     512

typedef __attribute__((ext_vector_type(8))) short short8;   // 8 bf16 (4 VGPRs)
typedef __attribute__((ext_vector_type(4))) float floatx4;  // MFMA C/D frag

static __device__ __forceinline__ uint16_t f2b(float f) {
    uint32_t x = __float_as_uint(f);
    x += 0x7fffu + ((x >> 16) & 1u);          // RNE
    return (uint16_t)(x >> 16);
}
static __device__ __forceinline__ float b2f(short u) {
    return __uint_as_float(((uint32_t)(uint16_t)u) << 16);
}

// ---------------- gather + cast embeddings to bf16 ----------------
__global__ void gather_cast(const int* __restrict__ u_gid, const int* __restrict__ i_gid,
                            const float* __restrict__ user_emb, const float* __restrict__ item_emb,
                            uint16_t* __restrict__ Xb)
{
    int t = blockIdx.x * 256 + threadIdx.x;   // over M_PAD*128 (4 elems each)
    int n = t >> 7;
    int j = (t & 127) << 2;
    uint2 o;
    if (n < N_NODES) {
        const float* src = (n < U_NODES) ? (user_emb + (size_t)u_gid[n] * HID)
                                         : (item_emb + (size_t)i_gid[n - U_NODES] * HID);
        float4 v = *(const float4*)(src + j);
        o.x = (uint32_t)f2b(v.x) | ((uint32_t)f2b(v.y) << 16);
        o.y = (uint32_t)f2b(v.z) | ((uint32_t)f2b(v.w) << 16);
    } else { o.x = 0u; o.y = 0u; }            // zero the pad rows
    *(uint2*)(Xb + (size_t)n * HID + j) = o;
}

// ---------------- W_ui|W_iu -> transposed bf16 (Wt[n][k]) ----------------
__global__ void prep_w(const float* __restrict__ Wui, const float* __restrict__ Wiu,
                       uint16_t* __restrict__ Wt)
{
    int t = blockIdx.x * 256 + threadIdx.x;   // 1024*512
    int n = t >> 9, k = t & 511;
    float v = (n < 512) ? Wui[k * 512 + n] : Wiu[k * 512 + (n - 512)];
    Wt[(size_t)n * 512 + k] = f2b(v);
}

// ---------------- bf16 GEMM: F[M_PAD,1024] = Xb[M_PAD,512] @ Wt^T ----------------
__global__ __launch_bounds__(256) void gemm_bf16(const uint16_t* __restrict__ Xb,
                                                 const uint16_t* __restrict__ Wt,
                                                 uint16_t* __restrict__ F)
{
    __shared__ __align__(16) uint16_t As[128 * 32];  // [row][k]
    __shared__ __align__(16) uint16_t Bs[128 * 32];  // [n][k]
    const int tid = threadIdx.x;
    const int wave = tid >> 6, lane = tid & 63;
    const int m0 = (blockIdx.x >> 3) * 128;
    const int n0 = (blockIdx.x & 7) * 128;
    const int wm = (wave & 1) * 64;
    const int wn = (wave >> 1) * 64;

    // staging: chunk c = i*256 + wave*64 + lane ; lds byte = c*16 ; row=c>>2, sub=c&3
    const int c0 = wave * 64 + lane;
    const int c1 = c0 + 256;
    const uint16_t* gA0 = Xb + (size_t)(m0 + (c0 >> 2)) * HID + (c0 & 3) * 8;
    const uint16_t* gA1 = Xb + (size_t)(m0 + (c1 >> 2)) * HID + (c1 & 3) * 8;
    const uint16_t* gB0 = Wt + (size_t)(n0 + (c0 >> 2)) * HID + (c0 & 3) * 8;
    const uint16_t* gB1 = Wt + (size_t)(n0 + (c1 >> 2)) * HID + (c1 & 3) * 8;
    uint16_t* lA0 = As + wave * 512;          // byte offset wave*1024
    uint16_t* lA1 = As + 2048 + wave * 512;   // byte offset 4096 + wave*1024
    uint16_t* lB0 = Bs + wave * 512;
    uint16_t* lB1 = Bs + 2048 + wave * 512;

    floatx4 zero = {0.f, 0.f, 0.f, 0.f};
    floatx4 acc[4][4];
    #pragma unroll
    for (int a = 0; a < 4; ++a)
        #pragma unroll
        for (int b = 0; b < 4; ++b) acc[a][b] = zero;

    const int r = lane & 15, quad = lane >> 4;

    for (int k0 = 0; k0 < HID; k0 += 32) {
        __syncthreads();
        __builtin_amdgcn_global_load_lds((const __attribute__((address_space(1))) void*)(gA0 + k0),
                                         (__attribute__((address_space(3))) void*)lA0, 16, 0, 0);
        __builtin_amdgcn_global_load_lds((const __attribute__((address_space(1))) void*)(gA1 + k0),
                                         (__attribute__((address_space(3))) void*)lA1, 16, 0, 0);
        __builtin_amdgcn_global_load_lds((const __attribute__((address_space(1))) void*)(gB0 + k0),
                                         (__attribute__((address_space(3))) void*)lB0, 16, 0, 0);
        __builtin_amdgcn_global_load_lds((const __attribute__((address_space(1))) void*)(gB1 + k0),
                                         (__attribute__((address_space(3))) void*)lB1, 16, 0, 0);
        __syncthreads();
        short8 af[4], bf[4];
        #pragma unroll
        for (int tm = 0; tm < 4; ++tm)
            af[tm] = *(const short8*)&As[(wm + tm * 16 + r) * 32 + quad * 8];
        #pragma unroll
        for (int tn = 0; tn < 4; ++tn)
            bf[tn] = *(const short8*)&Bs[(wn + tn * 16 + r) * 32 + quad * 8];
        #pragma unroll
        for (int tm = 0; tm < 4; ++tm)
            #pragma unroll
            for (int tn = 0; tn < 4; ++tn)
                acc[tm][tn] = __builtin_amdgcn_mfma_f32_16x16x32_bf16(af[tm], bf[tn], acc[tm][tn], 0, 0, 0);
    }
    // C/D layout: col = lane&15, row = quad*4 + reg
    #pragma unroll
    for (int tm = 0; tm < 4; ++tm) {
        #pragma unroll
        for (int rr = 0; rr < 4; ++rr) {
            int row = m0 + wm + tm * 16 + quad * 4 + rr;
            if (row < N_NODES) {
                #pragma unroll
                for (int tn = 0; tn < 4; ++tn) {
                    int col = n0 + wn + tn * 16 + r;
                    F[(size_t)row * 1024 + col] = f2b(acc[tm][tn][rr]);
                }
            }
        }
    }
}

// ---------------- per-node attention logits ----------------
__global__ void elr_kernel(const uint16_t* __restrict__ F,
                           const float* __restrict__ al_ui, const float* __restrict__ ar_ui,
                           const float* __restrict__ al_iu, const float* __restrict__ ar_iu,
                           float* __restrict__ ELui, float* __restrict__ ERui,
                           float* __restrict__ ELiu, float* __restrict__ ERiu)
{
    int n = blockIdx.x * 4 + (threadIdx.x >> 6);
    if (n >= N_NODES) return;
    int lane = threadIdx.x & 63;
    int base = lane * 8;
    short8 a = *(const short8*)&F[(size_t)n * 1024 + base];
    short8 b = *(const short8*)&F[(size_t)n * 1024 + 512 + base];
    float s0 = 0.f, s1 = 0.f, s2 = 0.f, s3 = 0.f;
    #pragma unroll
    for (int j = 0; j < 8; ++j) {
        float fa = b2f(a[j]), fb = b2f(b[j]);
        s0 += fa * al_ui[base + j];
        s1 += fa * ar_ui[base + j];
        s2 += fb * al_iu[base + j];
        s3 += fb * ar_iu[base + j];
    }
    #pragma unroll
    for (int d = 1; d < 8; d <<= 1) {
        s0 += __shfl_xor(s0, d, 8);
        s1 += __shfl_xor(s1, d, 8);
        s2 += __shfl_xor(s2, d, 8);
        s3 += __shfl_xor(s3, d, 8);
    }
    if ((lane & 7) == 0) {
        int h = lane >> 3;
        ELui[n * 8 + h] = s0;
        ERui[n * 8 + h] = s1;
        ELiu[n * 8 + h] = s2;
        ERiu[n * 8 + h] = s3;
    }
}

// ---------------- CSR build ----------------
__global__ void hist_kernel(const int* __restrict__ src_u, const int* __restrict__ dst_i,
                            int* __restrict__ counts_i, int* __restrict__ counts_u)
{
    int e = blockIdx.x * 256 + threadIdx.x;
    if (e >= E_EDGES) return;
    atomicAdd(&counts_i[dst_i[e]], 1);
    atomicAdd(&counts_u[src_u[e]], 1);
}

__global__ __launch_bounds__(1024) void scan_kernel(const int* __restrict__ counts_i,
                                                    const int* __restrict__ counts_u,
                                                    int* __restrict__ offs_i, int* __restrict__ cur_i,
                                                    int* __restrict__ offs_u, int* __restrict__ cur_u)
{
    const int* counts; int n; int* offs; int* cur;
    if (blockIdx.x == 0) { counts = counts_i; n = I_NODES; offs = offs_i; cur = cur_i; }
    else                 { counts = counts_u; n = U_NODES; offs = offs_u; cur = cur_u; }
    __shared__ int wsum[16];
    int tid = threadIdx.x, lane = tid & 63, w = tid >> 6;
    int carry = 0;
    for (int base = 0; base < n; base += 1024) {
        int i = base + tid;
        int v = (i < n) ? counts[i] : 0;
        int x = v;
        #pragma unroll
        for (int d = 1; d < 64; d <<= 1) {
            int y = __shfl_up(x, d, 64);
            if (lane >= d) x += y;
        }
        if (lane == 63) wsum[w] = x;
        __syncthreads();
        if (w == 0) {
            int s = (lane < 16) ? wsum[lane] : 0;
            #pragma unroll
            for (int d = 1; d < 16; d <<= 1) {
                int y = __shfl_up(s, d, 16);
                if ((lane & 15) >= d) s += y;
            }
            if (lane < 16) wsum[lane] = s;    // inclusive per-wave sums
        }
        __syncthreads();
        int wexcl = (w == 0) ? 0 : wsum[w - 1];
        int excl = carry + wexcl + (x - v);
        if (i < n) { offs[i] = excl; cur[i] = excl; }
        int tot = wsum[15];
        __syncthreads();
        carry += tot;
    }
    if (tid == 0) offs[n] = carry;
}

__global__ void scatter_kernel(const int* __restrict__ src_u, const int* __restrict__ dst_i,
                               int* __restrict__ cur_i, int* __restrict__ cur_u,
                               int* __restrict__ sorted_ui, int* __restrict__ sorted_iu)
{
    int e = blockIdx.x * 256 + threadIdx.x;
    if (e >= E_EDGES) return;
    int s = src_u[e], d = dst_i[e];
    int p = atomicAdd(&cur_i[d], 1);
    sorted_ui[p] = s;                  // user node id
    int q = atomicAdd(&cur_u[s], 1);
    sorted_iu[q] = U_NODES + d;        // item node id
}

// ---------------- per-destination softmax + aggregate (one wave per dst) ----------------
__global__ void agg_kernel(const int* __restrict__ offs, const int* __restrict__ srcs,
                           const uint16_t* __restrict__ F, int colbase,
                           const float* __restrict__ EL, const float* __restrict__ ER,
                           const float* __restrict__ bias, float* __restrict__ out,
                           float* __restrict__ partial, int n_dst, int mean_mode)
{
    int dst = blockIdx.x * 4 + (threadIdx.x >> 6);
    if (dst >= n_dst) return;
    int lane = threadIdx.x & 63;
    int h = lane >> 3;
    int j0 = offs[dst], j1 = offs[dst + 1];
    float er = ER[dst * 8 + h];
    float den = 0.f;
    #pragma unroll 2
    for (int j = j0; j < j1; ++j) {
        int s = srcs[j];
        float e = EL[s * 8 + h] + er;
        e = (e >= 0.f) ? e : 0.2f * e;
        den += __expf(e);
    }
    float inv = (j1 > j0) ? (1.f / den) : 0.f;
    float acc[8] = {0.f, 0.f, 0.f, 0.f, 0.f, 0.f, 0.f, 0.f};
    int fb = colbase + lane * 8;
    #pragma unroll 2
    for (int j = j0; j < j1; ++j) {
        int s = srcs[j];
        float e = EL[s * 8 + h] + er;
        e = (e >= 0.f) ? e : 0.2f * e;
        float wgt = __expf(e) * inv;
        short8 fv = *(const short8*)&F[(size_t)s * 1024 + fb];
        #pragma unroll
        for (int q = 0; q < 8; ++q) acc[q] += wgt * b2f(fv[q]);
    }
    int col = lane * 8;
    if (mean_mode) {
        float* p = partial + (size_t)(dst & 63) * 512 + col;
        #pragma unroll
        for (int q = 0; q < 8; ++q) atomicAdd(&p[q], acc[q]);   // bias folded in later
    } else {
        float* o = out + (size_t)dst * 1024 + col;
        #pragma unroll
        for (int q = 0; q < 8; ++q) o[q] = acc[q] + bias[col + q];
    }
}

// ---------------- item mean finalize + broadcast ----------------
__global__ void meanvec_kernel(const float* __restrict__ partial, const float* __restrict__ b_ui,
                               float* __restrict__ mean_vec)
{
    int c = threadIdx.x;   // 512
    float s = 0.f;
    for (int p = 0; p < 64; ++p) s += partial[p * 512 + c];
    mean_vec[c] = s * (1.0f / (float)I_NODES) + b_ui[c];
}

__global__ void bcast_kernel(const float* __restrict__ mean_vec, float* __restrict__ out)
{
    int t = blockIdx.x * 256 + threadIdx.x;   // U*128
    int u = t >> 7, q = t & 127;
    float4 v = ((const float4*)mean_vec)[q];
    *(float4*)(out + (size_t)u * 1024 + 512 + q * 4) = v;
}

extern "C" void kernel_launch(void* const* d_in, const int* in_sizes, int n_in,
                              void* d_out, int out_size, void* d_ws, size_t ws_size,
                              hipStream_t stream)
{
    const int*   u_gid    = (const int*)d_in[0];
    const int*   i_gid    = (const int*)d_in[1];
    const int*   src_u    = (const int*)d_in[2];
    const int*   dst_i    = (const int*)d_in[3];
    const float* user_emb = (const float*)d_in[4];
    const float* item_emb = (const float*)d_in[5];
    const float* W_ui     = (const float*)d_in[6];
    const float* al_ui    = (const float*)d_in[7];
    const float* ar_ui    = (const float*)d_in[8];
    const float* b_ui     = (const float*)d_in[9];
    const float* W_iu     = (const float*)d_in[10];
    const float* al_iu    = (const float*)d_in[11];
    const float* ar_iu    = (const float*)d_in[12];
    const float* b_iu     = (const float*)d_in[13];
    float* out = (float*)d_out;

    char* ws = (char*)d_ws;
    size_t off = 0;
    auto alloc = [&](size_t bytes) -> void* {
        void* p = ws + off;
        off = (off + bytes + 255) & ~(size_t)255;
        return p;
    };
    uint16_t* Xb   = (uint16_t*)alloc((size_t)M_PAD * 512 * 2);
    uint16_t* Wt   = (uint16_t*)alloc((size_t)1024 * 512 * 2);
    uint16_t* F    = (uint16_t*)alloc((size_t)M_PAD * 1024 * 2);
    float* ELui    = (float*)alloc((size_t)N_NODES * 8 * 4);
    float* ERui    = (float*)alloc((size_t)N_NODES * 8 * 4);
    float* ELiu    = (float*)alloc((size_t)N_NODES * 8 * 4);
    float* ERiu    = (float*)alloc((size_t)N_NODES * 8 * 4);
    int* offs_i    = (int*)alloc((size_t)(I_NODES + 1) * 4);
    int* cur_i     = (int*)alloc((size_t)I_NODES * 4);
    int* offs_u    = (int*)alloc((size_t)(U_NODES + 1) * 4);
    int* cur_u     = (int*)alloc((size_t)U_NODES * 4);
    int* sorted_ui = (int*)alloc((size_t)E_EDGES * 4);
    int* sorted_iu = (int*)alloc((size_t)E_EDGES * 4);
    // zeroed region (contiguous): counts_i, counts_u, partial
    char* zptr = ws + off;
    int*   counts_i = (int*)alloc((size_t)I_NODES * 4);
    int*   counts_u = (int*)alloc((size_t)U_NODES * 4);
    float* partial  = (float*)alloc((size_t)64 * 512 * 4);
    size_t zbytes = (size_t)((ws + off) - zptr);
    float* mean_vec = (float*)alloc(512 * 4);
    (void)ws_size; (void)in_sizes; (void)n_in; (void)out_size;

    hipMemsetAsync(zptr, 0, zbytes, stream);
    prep_w<<<2048, 256, 0, stream>>>(W_ui, W_iu, Wt);
    gather_cast<<<M_PAD * 128 / 256, 256, 0, stream>>>(u_gid, i_gid, user_emb, item_emb, Xb);
    gemm_bf16<<<(M_PAD / 128) * 8, 256, 0, stream>>>(Xb, Wt, F);
    elr_kernel<<<(N_NODES + 3) / 4, 256, 0, stream>>>(F, al_ui, ar_ui, al_iu, ar_iu,
                                                      ELui, ERui, ELiu, ERiu);
    hist_kernel<<<(E_EDGES + 255) / 256, 256, 0, stream>>>(src_u, dst_i, counts_i, counts_u);
    scan_kernel<<<2, 1024, 0, stream>>>(counts_i, counts_u, offs_i, cur_i, offs_u, cur_u);
    scatter_kernel<<<(E_EDGES + 255) / 256, 256, 0, stream>>>(src_u, dst_i, cur_i, cur_u,
                                                              sorted_ui, sorted_iu);
    // user -> item ('interact'): dst = items, only the column-mean survives
    agg_kernel<<<(I_NODES + 3) / 4, 256, 0, stream>>>(offs_i, sorted_ui, F, 0,
                                                      ELui, ERui + (size_t)U_NODES * 8,
                                                      nullptr, nullptr, partial, I_NODES, 1);
    // item -> user ('interact_rev'): dst = users, writes out[:, 0:512]
    agg_kernel<<<(U_NODES + 3) / 4, 256, 0, stream>>>(offs_u, sorted_iu, F, 512,
                                                      ELiu, ERiu,
                                                      b_iu, out, nullptr, U_NODES, 0);
    meanvec_kernel<<<1, 512, 0, stream>>>(partial, b_ui, mean_vec);
    bcast_kernel<<<U_NODES * 128 / 256, 256, 0, stream>>>(mean_vec, out);
}

// Round 2
// 1043.834 us; speedup vs baseline: 1.0191x; 1.0191x over previous
//
#include <hip/hip_runtime.h>
#include <hip/hip_bf16.h>
#include <stdint.h>

#define U_NODES 50000
#define I_NODES 20000
#define N_NODES 70000
#define M_PAD   70016      // 547 * 128
#define E_EDGES 400000
#define HID     512

typedef __attribute__((ext_vector_type(8))) short short8;   // 8 bf16 (4 VGPRs)
typedef __attribute__((ext_vector_type(4))) float floatx4;  // MFMA C/D frag

static __device__ __forceinline__ uint16_t f2b(float f) {
    uint32_t x = __float_as_uint(f);
    x += 0x7fffu + ((x >> 16) & 1u);          // RNE
    return (uint16_t)(x >> 16);
}
static __device__ __forceinline__ float b2f(short u) {
    return __uint_as_float(((uint32_t)(uint16_t)u) << 16);
}

// ---------------- gather + cast embeddings to bf16 ----------------
__global__ void gather_cast(const int* __restrict__ u_gid, const int* __restrict__ i_gid,
                            const float* __restrict__ user_emb, const float* __restrict__ item_emb,
                            uint16_t* __restrict__ Xb)
{
    int t = blockIdx.x * 256 + threadIdx.x;   // over M_PAD*128 (4 elems each)
    int n = t >> 7;
    int j = (t & 127) << 2;
    uint2 o;
    if (n < N_NODES) {
        const float* src = (n < U_NODES) ? (user_emb + (size_t)u_gid[n] * HID)
                                         : (item_emb + (size_t)i_gid[n - U_NODES] * HID);
        float4 v = *(const float4*)(src + j);
        o.x = (uint32_t)f2b(v.x) | ((uint32_t)f2b(v.y) << 16);
        o.y = (uint32_t)f2b(v.z) | ((uint32_t)f2b(v.w) << 16);
    } else { o.x = 0u; o.y = 0u; }            // zero the pad rows
    *(uint2*)(Xb + (size_t)n * HID + j) = o;
}

// ---------------- W_ui|W_iu -> transposed bf16 (Wt[n][k]) ----------------
__global__ void prep_w(const float* __restrict__ Wui, const float* __restrict__ Wiu,
                       uint16_t* __restrict__ Wt)
{
    int t = blockIdx.x * 256 + threadIdx.x;   // 1024*512
    int n = t >> 9, k = t & 511;
    float v = (n < 512) ? Wui[k * 512 + n] : Wiu[k * 512 + (n - 512)];
    Wt[(size_t)n * 512 + k] = f2b(v);
}

// ---------------- bf16 GEMM: F[M_PAD,1024] = Xb[M_PAD,512] @ Wt^T ----------------
__global__ __launch_bounds__(256) void gemm_bf16(const uint16_t* __restrict__ Xb,
                                                 const uint16_t* __restrict__ Wt,
                                                 uint16_t* __restrict__ F)
{
    __shared__ __align__(16) uint16_t As[128 * 32];  // [row][k]
    __shared__ __align__(16) uint16_t Bs[128 * 32];  // [n][k]
    const int tid = threadIdx.x;
    const int wave = tid >> 6, lane = tid & 63;
    const int m0 = (blockIdx.x >> 3) * 128;
    const int n0 = (blockIdx.x & 7) * 128;
    const int wm = (wave & 1) * 64;
    const int wn = (wave >> 1) * 64;

    const int c0 = wave * 64 + lane;
    const int c1 = c0 + 256;
    const uint16_t* gA0 = Xb + (size_t)(m0 + (c0 >> 2)) * HID + (c0 & 3) * 8;
    const uint16_t* gA1 = Xb + (size_t)(m0 + (c1 >> 2)) * HID + (c1 & 3) * 8;
    const uint16_t* gB0 = Wt + (size_t)(n0 + (c0 >> 2)) * HID + (c0 & 3) * 8;
    const uint16_t* gB1 = Wt + (size_t)(n0 + (c1 >> 2)) * HID + (c1 & 3) * 8;
    uint16_t* lA0 = As + wave * 512;
    uint16_t* lA1 = As + 2048 + wave * 512;
    uint16_t* lB0 = Bs + wave * 512;
    uint16_t* lB1 = Bs + 2048 + wave * 512;

    floatx4 zero = {0.f, 0.f, 0.f, 0.f};
    floatx4 acc[4][4];
    #pragma unroll
    for (int a = 0; a < 4; ++a)
        #pragma unroll
        for (int b = 0; b < 4; ++b) acc[a][b] = zero;

    const int r = lane & 15, quad = lane >> 4;

    for (int k0 = 0; k0 < HID; k0 += 32) {
        __syncthreads();
        __builtin_amdgcn_global_load_lds((const __attribute__((address_space(1))) void*)(gA0 + k0),
                                         (__attribute__((address_space(3))) void*)lA0, 16, 0, 0);
        __builtin_amdgcn_global_load_lds((const __attribute__((address_space(1))) void*)(gA1 + k0),
                                         (__attribute__((address_space(3))) void*)lA1, 16, 0, 0);
        __builtin_amdgcn_global_load_lds((const __attribute__((address_space(1))) void*)(gB0 + k0),
                                         (__attribute__((address_space(3))) void*)lB0, 16, 0, 0);
        __builtin_amdgcn_global_load_lds((const __attribute__((address_space(1))) void*)(gB1 + k0),
                                         (__attribute__((address_space(3))) void*)lB1, 16, 0, 0);
        __syncthreads();
        short8 af[4], bf[4];
        #pragma unroll
        for (int tm = 0; tm < 4; ++tm)
            af[tm] = *(const short8*)&As[(wm + tm * 16 + r) * 32 + quad * 8];
        #pragma unroll
        for (int tn = 0; tn < 4; ++tn)
            bf[tn] = *(const short8*)&Bs[(wn + tn * 16 + r) * 32 + quad * 8];
        #pragma unroll
        for (int tm = 0; tm < 4; ++tm)
            #pragma unroll
            for (int tn = 0; tn < 4; ++tn)
                acc[tm][tn] = __builtin_amdgcn_mfma_f32_16x16x32_bf16(af[tm], bf[tn], acc[tm][tn], 0, 0, 0);
    }
    // C/D layout: col = lane&15, row = quad*4 + reg
    #pragma unroll
    for (int tm = 0; tm < 4; ++tm) {
        #pragma unroll
        for (int rr = 0; rr < 4; ++rr) {
            int row = m0 + wm + tm * 16 + quad * 4 + rr;
            if (row < N_NODES) {
                #pragma unroll
                for (int tn = 0; tn < 4; ++tn) {
                    int col = n0 + wn + tn * 16 + r;
                    F[(size_t)row * 1024 + col] = f2b(acc[tm][tn][rr]);
                }
            }
        }
    }
}

// ---------------- per-node attention logits ----------------
__global__ void elr_kernel(const uint16_t* __restrict__ F,
                           const float* __restrict__ al_ui, const float* __restrict__ ar_ui,
                           const float* __restrict__ al_iu, const float* __restrict__ ar_iu,
                           float* __restrict__ ELui, float* __restrict__ ERui,
                           float* __restrict__ ELiu, float* __restrict__ ERiu)
{
    int n = blockIdx.x * 4 + (threadIdx.x >> 6);
    if (n >= N_NODES) return;
    int lane = threadIdx.x & 63;
    int base = lane * 8;
    short8 a = *(const short8*)&F[(size_t)n * 1024 + base];
    short8 b = *(const short8*)&F[(size_t)n * 1024 + 512 + base];
    float s0 = 0.f, s1 = 0.f, s2 = 0.f, s3 = 0.f;
    #pragma unroll
    for (int j = 0; j < 8; ++j) {
        float fa = b2f(a[j]), fb = b2f(b[j]);
        s0 += fa * al_ui[base + j];
        s1 += fa * ar_ui[base + j];
        s2 += fb * al_iu[base + j];
        s3 += fb * ar_iu[base + j];
    }
    #pragma unroll
    for (int d = 1; d < 8; d <<= 1) {
        s0 += __shfl_xor(s0, d, 8);
        s1 += __shfl_xor(s1, d, 8);
        s2 += __shfl_xor(s2, d, 8);
        s3 += __shfl_xor(s3, d, 8);
    }
    if ((lane & 7) == 0) {
        int h = lane >> 3;
        ELui[n * 8 + h] = s0;
        ERui[n * 8 + h] = s1;
        ELiu[n * 8 + h] = s2;
        ERiu[n * 8 + h] = s3;
    }
}

// ---------------- CSR build ----------------
__global__ void hist_kernel(const int* __restrict__ src_u, const int* __restrict__ dst_i,
                            int* __restrict__ counts_i, int* __restrict__ counts_u)
{
    int e = blockIdx.x * 256 + threadIdx.x;
    if (e >= E_EDGES) return;
    atomicAdd(&counts_i[dst_i[e]], 1);
    atomicAdd(&counts_u[src_u[e]], 1);
}

__global__ __launch_bounds__(1024) void scan_kernel(const int* __restrict__ counts_i,
                                                    const int* __restrict__ counts_u,
                                                    int* __restrict__ offs_i, int* __restrict__ cur_i,
                                                    int* __restrict__ offs_u, int* __restrict__ cur_u)
{
    const int* counts; int n; int* offs; int* cur;
    if (blockIdx.x == 0) { counts = counts_i; n = I_NODES; offs = offs_i; cur = cur_i; }
    else                 { counts = counts_u; n = U_NODES; offs = offs_u; cur = cur_u; }
    __shared__ int wsum[16];
    int tid = threadIdx.x, lane = tid & 63, w = tid >> 6;
    int carry = 0;
    for (int base = 0; base < n; base += 1024) {
        int i = base + tid;
        int v = (i < n) ? counts[i] : 0;
        int x = v;
        #pragma unroll
        for (int d = 1; d < 64; d <<= 1) {
            int y = __shfl_up(x, d, 64);
            if (lane >= d) x += y;
        }
        if (lane == 63) wsum[w] = x;
        __syncthreads();
        if (w == 0) {
            int s = (lane < 16) ? wsum[lane] : 0;
            #pragma unroll
            for (int d = 1; d < 16; d <<= 1) {
                int y = __shfl_up(s, d, 16);
                if ((lane & 15) >= d) s += y;
            }
            if (lane < 16) wsum[lane] = s;    // inclusive per-wave sums
        }
        __syncthreads();
        int wexcl = (w == 0) ? 0 : wsum[w - 1];
        int excl = carry + wexcl + (x - v);
        if (i < n) { offs[i] = excl; cur[i] = excl; }
        int tot = wsum[15];
        __syncthreads();
        carry += tot;
    }
    if (tid == 0) offs[n] = carry;
}

// scatter + per-edge attention weights exp(leaky(el+er)) for both directions
__global__ void scatter_kernel(const int* __restrict__ src_u, const int* __restrict__ dst_i,
                               int* __restrict__ cur_i, int* __restrict__ cur_u,
                               int* __restrict__ sorted_ui, int* __restrict__ sorted_iu,
                               const float* __restrict__ ELui, const float* __restrict__ ERui,
                               const float* __restrict__ ELiu, const float* __restrict__ ERiu,
                               float* __restrict__ ex_ui, float* __restrict__ ex_iu)
{
    int e = blockIdx.x * 256 + threadIdx.x;
    if (e >= E_EDGES) return;
    int s = src_u[e], d = dst_i[e];
    int dn = U_NODES + d;
    int p = atomicAdd(&cur_i[d], 1);
    int q = atomicAdd(&cur_u[s], 1);
    sorted_ui[p] = s;                  // user node id (src for ui)
    sorted_iu[q] = dn;                 // item node id (src for iu)
    #pragma unroll
    for (int h = 0; h < 8; ++h) {
        float e1 = ELui[s * 8 + h] + ERui[dn * 8 + h];     // user -> item
        e1 = (e1 >= 0.f) ? e1 : 0.2f * e1;
        ex_ui[(size_t)p * 8 + h] = __expf(e1);
        float e2 = ELiu[dn * 8 + h] + ERiu[s * 8 + h];     // item -> user
        e2 = (e2 >= 0.f) ? e2 : 0.2f * e2;
        ex_iu[(size_t)q * 8 + h] = __expf(e2);
    }
}

// ---------------- unified per-destination softmax + aggregate ----------------
// wave per dst; grid covers item-dsts then user-dsts
#define IBLK ((I_NODES + 3) / 4)
#define UBLK ((U_NODES + 3) / 4)
__global__ __launch_bounds__(256) void agg2_kernel(
    const int* __restrict__ offs_i, const int* __restrict__ sorted_ui, const float* __restrict__ ex_ui,
    const int* __restrict__ offs_u, const int* __restrict__ sorted_iu, const float* __restrict__ ex_iu,
    const uint16_t* __restrict__ F, const float* __restrict__ b_iu,
    float* __restrict__ out, float* __restrict__ partial)
{
    int bid = blockIdx.x;
    int w = threadIdx.x >> 6, lane = threadIdx.x & 63;
    bool item_mode = bid < IBLK;
    const int* offs; const int* srcs; const float* ex; int dst, colbase, n_dst;
    if (item_mode) { offs = offs_i; srcs = sorted_ui; ex = ex_ui; dst = bid * 4 + w;          colbase = 0;   n_dst = I_NODES; }
    else           { offs = offs_u; srcs = sorted_iu; ex = ex_iu; dst = (bid - IBLK) * 4 + w; colbase = 512; n_dst = U_NODES; }
    if (dst >= n_dst) return;
    int h = lane >> 3;
    int j0 = offs[dst], j1 = offs[dst + 1];

    // ---- denominator: contiguous coalesced read of ex[j0*8 .. j1*8) ----
    float part = 0.f;
    for (int t = j0 * 8 + lane; t < j1 * 8; t += 64) part += ex[t];
    // lane holds partial for head (lane&7); reduce across the 8 lanes sharing lane&7
    part += __shfl_xor(part, 8);
    part += __shfl_xor(part, 16);
    part += __shfl_xor(part, 32);
    // exchange: lane needs den for head lane>>3, held by lane ((lane&7)<<3)|(lane>>3)
    float den = __shfl(part, ((lane & 7) << 3) | (lane >> 3));
    float inv = (j1 > j0) ? (1.f / den) : 0.f;

    // ---- accumulate: unroll x4, independent F-row gathers ----
    float acc[8] = {0.f, 0.f, 0.f, 0.f, 0.f, 0.f, 0.f, 0.f};
    const int fb = colbase + lane * 8;
    int j = j0;
    for (; j + 4 <= j1; j += 4) {
        int s0 = srcs[j], s1 = srcs[j + 1], s2 = srcs[j + 2], s3 = srcs[j + 3];
        float w0 = ex[(size_t)(j + 0) * 8 + h] * inv;
        float w1 = ex[(size_t)(j + 1) * 8 + h] * inv;
        float w2 = ex[(size_t)(j + 2) * 8 + h] * inv;
        float w3 = ex[(size_t)(j + 3) * 8 + h] * inv;
        short8 f0 = *(const short8*)&F[(size_t)s0 * 1024 + fb];
        short8 f1 = *(const short8*)&F[(size_t)s1 * 1024 + fb];
        short8 f2 = *(const short8*)&F[(size_t)s2 * 1024 + fb];
        short8 f3 = *(const short8*)&F[(size_t)s3 * 1024 + fb];
        #pragma unroll
        for (int q = 0; q < 8; ++q)
            acc[q] += w0 * b2f(f0[q]) + w1 * b2f(f1[q]) + w2 * b2f(f2[q]) + w3 * b2f(f3[q]);
    }
    for (; j < j1; ++j) {
        int s0 = srcs[j];
        float w0 = ex[(size_t)j * 8 + h] * inv;
        short8 f0 = *(const short8*)&F[(size_t)s0 * 1024 + fb];
        #pragma unroll
        for (int q = 0; q < 8; ++q) acc[q] += w0 * b2f(f0[q]);
    }

    int col = lane * 8;
    if (item_mode) {
        float* p = partial + (size_t)(dst & 63) * 512 + col;
        #pragma unroll
        for (int q = 0; q < 8; ++q) atomicAdd(&p[q], acc[q]);   // bias folded in later
    } else {
        float* o = out + (size_t)dst * 1024 + col;
        float4 v0 = {acc[0] + b_iu[col + 0], acc[1] + b_iu[col + 1],
                     acc[2] + b_iu[col + 2], acc[3] + b_iu[col + 3]};
        float4 v1 = {acc[4] + b_iu[col + 4], acc[5] + b_iu[col + 5],
                     acc[6] + b_iu[col + 6], acc[7] + b_iu[col + 7]};
        *(float4*)(o + 0) = v0;
        *(float4*)(o + 4) = v1;
    }
}

// ---------------- item mean finalize + broadcast ----------------
__global__ void meanvec_kernel(const float* __restrict__ partial, const float* __restrict__ b_ui,
                               float* __restrict__ mean_vec)
{
    int c = threadIdx.x;   // 512
    float s = 0.f;
    for (int p = 0; p < 64; ++p) s += partial[p * 512 + c];
    mean_vec[c] = s * (1.0f / (float)I_NODES) + b_ui[c];
}

__global__ void bcast_kernel(const float* __restrict__ mean_vec, float* __restrict__ out)
{
    int t = blockIdx.x * 256 + threadIdx.x;   // U*128
    int u = t >> 7, q = t & 127;
    float4 v = ((const float4*)mean_vec)[q];
    *(float4*)(out + (size_t)u * 1024 + 512 + q * 4) = v;
}

extern "C" void kernel_launch(void* const* d_in, const int* in_sizes, int n_in,
                              void* d_out, int out_size, void* d_ws, size_t ws_size,
                              hipStream_t stream)
{
    const int*   u_gid    = (const int*)d_in[0];
    const int*   i_gid    = (const int*)d_in[1];
    const int*   src_u    = (const int*)d_in[2];
    const int*   dst_i    = (const int*)d_in[3];
    const float* user_emb = (const float*)d_in[4];
    const float* item_emb = (const float*)d_in[5];
    const float* W_ui     = (const float*)d_in[6];
    const float* al_ui    = (const float*)d_in[7];
    const float* ar_ui    = (const float*)d_in[8];
    const float* b_ui     = (const float*)d_in[9];
    const float* W_iu     = (const float*)d_in[10];
    const float* al_iu    = (const float*)d_in[11];
    const float* ar_iu    = (const float*)d_in[12];
    const float* b_iu     = (const float*)d_in[13];
    float* out = (float*)d_out;

    char* ws = (char*)d_ws;
    size_t off = 0;
    auto alloc = [&](size_t bytes) -> void* {
        void* p = ws + off;
        off = (off + bytes + 255) & ~(size_t)255;
        return p;
    };
    uint16_t* Xb   = (uint16_t*)alloc((size_t)M_PAD * 512 * 2);
    uint16_t* Wt   = (uint16_t*)alloc((size_t)1024 * 512 * 2);
    uint16_t* F    = (uint16_t*)alloc((size_t)M_PAD * 1024 * 2);
    float* ELui    = (float*)alloc((size_t)N_NODES * 8 * 4);
    float* ERui    = (float*)alloc((size_t)N_NODES * 8 * 4);
    float* ELiu    = (float*)alloc((size_t)N_NODES * 8 * 4);
    float* ERiu    = (float*)alloc((size_t)N_NODES * 8 * 4);
    int* offs_i    = (int*)alloc((size_t)(I_NODES + 1) * 4);
    int* cur_i     = (int*)alloc((size_t)I_NODES * 4);
    int* offs_u    = (int*)alloc((size_t)(U_NODES + 1) * 4);
    int* cur_u     = (int*)alloc((size_t)U_NODES * 4);
    int* sorted_ui = (int*)alloc((size_t)E_EDGES * 4);
    int* sorted_iu = (int*)alloc((size_t)E_EDGES * 4);
    float* ex_ui   = (float*)alloc((size_t)E_EDGES * 8 * 4);
    float* ex_iu   = (float*)alloc((size_t)E_EDGES * 8 * 4);
    // zeroed region (contiguous): counts_i, counts_u, partial
    char* zptr = ws + off;
    int*   counts_i = (int*)alloc((size_t)I_NODES * 4);
    int*   counts_u = (int*)alloc((size_t)U_NODES * 4);
    float* partial  = (float*)alloc((size_t)64 * 512 * 4);
    size_t zbytes = (size_t)((ws + off) - zptr);
    float* mean_vec = (float*)alloc(512 * 4);
    (void)ws_size; (void)in_sizes; (void)n_in; (void)out_size;

    hipMemsetAsync(zptr, 0, zbytes, stream);
    prep_w<<<2048, 256, 0, stream>>>(W_ui, W_iu, Wt);
    gather_cast<<<M_PAD * 128 / 256, 256, 0, stream>>>(u_gid, i_gid, user_emb, item_emb, Xb);
    gemm_bf16<<<(M_PAD / 128) * 8, 256, 0, stream>>>(Xb, Wt, F);
    elr_kernel<<<(N_NODES + 3) / 4, 256, 0, stream>>>(F, al_ui, ar_ui, al_iu, ar_iu,
                                                      ELui, ERui, ELiu, ERiu);
    hist_kernel<<<(E_EDGES + 255) / 256, 256, 0, stream>>>(src_u, dst_i, counts_i, counts_u);
    scan_kernel<<<2, 1024, 0, stream>>>(counts_i, counts_u, offs_i, cur_i, offs_u, cur_u);
    scatter_kernel<<<(E_EDGES + 255) / 256, 256, 0, stream>>>(src_u, dst_i, cur_i, cur_u,
                                                              sorted_ui, sorted_iu,
                                                              ELui, ERui, ELiu, ERiu,
                                                              ex_ui, ex_iu);
    agg2_kernel<<<IBLK + UBLK, 256, 0, stream>>>(offs_i, sorted_ui, ex_ui,
                                                 offs_u, sorted_iu, ex_iu,
                                                 F, b_iu, out, partial);
    meanvec_kernel<<<1, 512, 0, stream>>>(partial, b_ui, mean_vec);
    bcast_kernel<<<U_NODES * 128 / 256, 256, 0, stream>>>(mean_vec, out);
}

// Round 3
// 914.985 us; speedup vs baseline: 1.1626x; 1.1408x over previous
//
#include <hip/hip_runtime.h>
#include <hip/hip_bf16.h>
#include <stdint.h>

#define U_NODES 50000
#define I_NODES 20000
#define N_NODES 70000
#define M_PAD   70016      // 547 * 128
#define E_EDGES 400000
#define HID     512

typedef __attribute__((ext_vector_type(8))) short short8;   // 8 bf16 (4 VGPRs)
typedef __attribute__((ext_vector_type(4))) float floatx4;  // MFMA C/D frag

static __device__ __forceinline__ uint16_t f2b(float f) {
    uint32_t x = __float_as_uint(f);
    x += 0x7fffu + ((x >> 16) & 1u);          // RNE
    return (uint16_t)(x >> 16);
}
static __device__ __forceinline__ float b2f(short u) {
    return __uint_as_float(((uint32_t)(uint16_t)u) << 16);
}

// ---------------- gather + cast embeddings to bf16 ----------------
__global__ void gather_cast(const int* __restrict__ u_gid, const int* __restrict__ i_gid,
                            const float* __restrict__ user_emb, const float* __restrict__ item_emb,
                            uint16_t* __restrict__ Xb)
{
    int t = blockIdx.x * 256 + threadIdx.x;   // over M_PAD*128 (4 elems each)
    int n = t >> 7;
    int j = (t & 127) << 2;
    uint2 o;
    if (n < N_NODES) {
        const float* src = (n < U_NODES) ? (user_emb + (size_t)u_gid[n] * HID)
                                         : (item_emb + (size_t)i_gid[n - U_NODES] * HID);
        float4 v = *(const float4*)(src + j);
        o.x = (uint32_t)f2b(v.x) | ((uint32_t)f2b(v.y) << 16);
        o.y = (uint32_t)f2b(v.z) | ((uint32_t)f2b(v.w) << 16);
    } else { o.x = 0u; o.y = 0u; }            // zero the pad rows
    *(uint2*)(Xb + (size_t)n * HID + j) = o;
}

// ---------------- W_ui|W_iu -> transposed bf16 (Wt[n][k]) ----------------
__global__ void prep_w(const float* __restrict__ Wui, const float* __restrict__ Wiu,
                       uint16_t* __restrict__ Wt)
{
    int t = blockIdx.x * 256 + threadIdx.x;   // 1024*512
    int n = t >> 9, k = t & 511;
    float v = (n < 512) ? Wui[k * 512 + n] : Wiu[k * 512 + (n - 512)];
    Wt[(size_t)n * 512 + k] = f2b(v);
}

// ---------------- bf16 GEMM: F[M_PAD,1024] = Xb[M_PAD,512] @ Wt^T ----------------
__global__ __launch_bounds__(256) void gemm_bf16(const uint16_t* __restrict__ Xb,
                                                 const uint16_t* __restrict__ Wt,
                                                 uint16_t* __restrict__ F)
{
    __shared__ __align__(16) uint16_t As[128 * 32];  // [row][k]
    __shared__ __align__(16) uint16_t Bs[128 * 32];  // [n][k]
    const int tid = threadIdx.x;
    const int wave = tid >> 6, lane = tid & 63;
    const int m0 = (blockIdx.x >> 3) * 128;
    const int n0 = (blockIdx.x & 7) * 128;
    const int wm = (wave & 1) * 64;
    const int wn = (wave >> 1) * 64;

    const int c0 = wave * 64 + lane;
    const int c1 = c0 + 256;
    const uint16_t* gA0 = Xb + (size_t)(m0 + (c0 >> 2)) * HID + (c0 & 3) * 8;
    const uint16_t* gA1 = Xb + (size_t)(m0 + (c1 >> 2)) * HID + (c1 & 3) * 8;
    const uint16_t* gB0 = Wt + (size_t)(n0 + (c0 >> 2)) * HID + (c0 & 3) * 8;
    const uint16_t* gB1 = Wt + (size_t)(n0 + (c1 >> 2)) * HID + (c1 & 3) * 8;
    uint16_t* lA0 = As + wave * 512;
    uint16_t* lA1 = As + 2048 + wave * 512;
    uint16_t* lB0 = Bs + wave * 512;
    uint16_t* lB1 = Bs + 2048 + wave * 512;

    floatx4 zero = {0.f, 0.f, 0.f, 0.f};
    floatx4 acc[4][4];
    #pragma unroll
    for (int a = 0; a < 4; ++a)
        #pragma unroll
        for (int b = 0; b < 4; ++b) acc[a][b] = zero;

    const int r = lane & 15, quad = lane >> 4;

    for (int k0 = 0; k0 < HID; k0 += 32) {
        __syncthreads();
        __builtin_amdgcn_global_load_lds((const __attribute__((address_space(1))) void*)(gA0 + k0),
                                         (__attribute__((address_space(3))) void*)lA0, 16, 0, 0);
        __builtin_amdgcn_global_load_lds((const __attribute__((address_space(1))) void*)(gA1 + k0),
                                         (__attribute__((address_space(3))) void*)lA1, 16, 0, 0);
        __builtin_amdgcn_global_load_lds((const __attribute__((address_space(1))) void*)(gB0 + k0),
                                         (__attribute__((address_space(3))) void*)lB0, 16, 0, 0);
        __builtin_amdgcn_global_load_lds((const __attribute__((address_space(1))) void*)(gB1 + k0),
                                         (__attribute__((address_space(3))) void*)lB1, 16, 0, 0);
        __syncthreads();
        short8 af[4], bf[4];
        #pragma unroll
        for (int tm = 0; tm < 4; ++tm)
            af[tm] = *(const short8*)&As[(wm + tm * 16 + r) * 32 + quad * 8];
        #pragma unroll
        for (int tn = 0; tn < 4; ++tn)
            bf[tn] = *(const short8*)&Bs[(wn + tn * 16 + r) * 32 + quad * 8];
        #pragma unroll
        for (int tm = 0; tm < 4; ++tm)
            #pragma unroll
            for (int tn = 0; tn < 4; ++tn)
                acc[tm][tn] = __builtin_amdgcn_mfma_f32_16x16x32_bf16(af[tm], bf[tn], acc[tm][tn], 0, 0, 0);
    }
    // C/D layout: col = lane&15, row = quad*4 + reg
    #pragma unroll
    for (int tm = 0; tm < 4; ++tm) {
        #pragma unroll
        for (int rr = 0; rr < 4; ++rr) {
            int row = m0 + wm + tm * 16 + quad * 4 + rr;
            if (row < N_NODES) {
                #pragma unroll
                for (int tn = 0; tn < 4; ++tn) {
                    int col = n0 + wn + tn * 16 + r;
                    F[(size_t)row * 1024 + col] = f2b(acc[tm][tn][rr]);
                }
            }
        }
    }
}

// ---------------- per-node attention logits ----------------
__global__ void elr_kernel(const uint16_t* __restrict__ F,
                           const float* __restrict__ al_ui, const float* __restrict__ ar_ui,
                           const float* __restrict__ al_iu, const float* __restrict__ ar_iu,
                           float* __restrict__ ELui, float* __restrict__ ERui,
                           float* __restrict__ ELiu, float* __restrict__ ERiu)
{
    int n = blockIdx.x * 4 + (threadIdx.x >> 6);
    if (n >= N_NODES) return;
    int lane = threadIdx.x & 63;
    int base = lane * 8;
    short8 a = *(const short8*)&F[(size_t)n * 1024 + base];
    short8 b = *(const short8*)&F[(size_t)n * 1024 + 512 + base];
    float s0 = 0.f, s1 = 0.f, s2 = 0.f, s3 = 0.f;
    #pragma unroll
    for (int j = 0; j < 8; ++j) {
        float fa = b2f(a[j]), fb = b2f(b[j]);
        s0 += fa * al_ui[base + j];
        s1 += fa * ar_ui[base + j];
        s2 += fb * al_iu[base + j];
        s3 += fb * ar_iu[base + j];
    }
    #pragma unroll
    for (int d = 1; d < 8; d <<= 1) {
        s0 += __shfl_xor(s0, d, 8);
        s1 += __shfl_xor(s1, d, 8);
        s2 += __shfl_xor(s2, d, 8);
        s3 += __shfl_xor(s3, d, 8);
    }
    if ((lane & 7) == 0) {
        int h = lane >> 3;
        ELui[n * 8 + h] = s0;
        ERui[n * 8 + h] = s1;
        ELiu[n * 8 + h] = s2;
        ERiu[n * 8 + h] = s3;
    }
}

// ---------------- CSR build ----------------
__global__ void hist_kernel(const int* __restrict__ src_u, const int* __restrict__ dst_i,
                            int* __restrict__ counts_i, int* __restrict__ counts_u)
{
    int e = blockIdx.x * 256 + threadIdx.x;
    if (e >= E_EDGES) return;
    atomicAdd(&counts_i[dst_i[e]], 1);
    atomicAdd(&counts_u[src_u[e]], 1);
}

__global__ __launch_bounds__(1024) void scan_kernel(const int* __restrict__ counts_i,
                                                    const int* __restrict__ counts_u,
                                                    int* __restrict__ offs_i, int* __restrict__ cur_i,
                                                    int* __restrict__ offs_u, int* __restrict__ cur_u)
{
    const int* counts; int n; int* offs; int* cur;
    if (blockIdx.x == 0) { counts = counts_i; n = I_NODES; offs = offs_i; cur = cur_i; }
    else                 { counts = counts_u; n = U_NODES; offs = offs_u; cur = cur_u; }
    __shared__ int wsum[16];
    int tid = threadIdx.x, lane = tid & 63, w = tid >> 6;
    int carry = 0;
    for (int base = 0; base < n; base += 1024) {
        int i = base + tid;
        int v = (i < n) ? counts[i] : 0;
        int x = v;
        #pragma unroll
        for (int d = 1; d < 64; d <<= 1) {
            int y = __shfl_up(x, d, 64);
            if (lane >= d) x += y;
        }
        if (lane == 63) wsum[w] = x;
        __syncthreads();
        if (w == 0) {
            int s = (lane < 16) ? wsum[lane] : 0;
            #pragma unroll
            for (int d = 1; d < 16; d <<= 1) {
                int y = __shfl_up(s, d, 16);
                if ((lane & 15) >= d) s += y;
            }
            if (lane < 16) wsum[lane] = s;    // inclusive per-wave sums
        }
        __syncthreads();
        int wexcl = (w == 0) ? 0 : wsum[w - 1];
        int excl = carry + wexcl + (x - v);
        if (i < n) { offs[i] = excl; cur[i] = excl; }
        int tot = wsum[15];
        __syncthreads();
        carry += tot;
    }
    if (tid == 0) offs[n] = carry;
}

// scatter + per-edge attention weights exp(leaky(el+er)) for both directions
__global__ void scatter_kernel(const int* __restrict__ src_u, const int* __restrict__ dst_i,
                               int* __restrict__ cur_i, int* __restrict__ cur_u,
                               int* __restrict__ sorted_ui, int* __restrict__ sorted_iu,
                               const float* __restrict__ ELui, const float* __restrict__ ERui,
                               const float* __restrict__ ELiu, const float* __restrict__ ERiu,
                               float* __restrict__ ex_ui, float* __restrict__ ex_iu)
{
    int e = blockIdx.x * 256 + threadIdx.x;
    if (e >= E_EDGES) return;
    int s = src_u[e], d = dst_i[e];
    int dn = U_NODES + d;
    int p = atomicAdd(&cur_i[d], 1);
    int q = atomicAdd(&cur_u[s], 1);
    sorted_ui[p] = s;                  // user node id (src for ui)
    sorted_iu[q] = dn;                 // item node id (src for iu)
    #pragma unroll
    for (int h = 0; h < 8; ++h) {
        float e1 = ELui[s * 8 + h] + ERui[dn * 8 + h];     // user -> item
        e1 = (e1 >= 0.f) ? e1 : 0.2f * e1;
        ex_ui[(size_t)p * 8 + h] = __expf(e1);
        float e2 = ELiu[dn * 8 + h] + ERiu[s * 8 + h];     // item -> user
        e2 = (e2 >= 0.f) ? e2 : 0.2f * e2;
        ex_iu[(size_t)q * 8 + h] = __expf(e2);
    }
}

// ---------------- unified per-destination softmax + aggregate (single pass) ----------------
// wave per dst; grid covers item-dsts then user-dsts. No atomics: item rows
// stream to itemF and are tree-reduced afterwards.
#define IBLK ((I_NODES + 3) / 4)
#define UBLK ((U_NODES + 3) / 4)
__global__ __launch_bounds__(256) void agg3_kernel(
    const int* __restrict__ offs_i, const int* __restrict__ sorted_ui, const float* __restrict__ ex_ui,
    const int* __restrict__ offs_u, const int* __restrict__ sorted_iu, const float* __restrict__ ex_iu,
    const uint16_t* __restrict__ F, const float* __restrict__ b_iu,
    float* __restrict__ out, float* __restrict__ itemF)
{
    int bid = blockIdx.x;
    int w = threadIdx.x >> 6, lane = threadIdx.x & 63;
    bool item_mode = bid < IBLK;
    const int* offs; const int* srcs; const float* ex; int dst, colbase, n_dst;
    if (item_mode) { offs = offs_i; srcs = sorted_ui; ex = ex_ui; dst = bid * 4 + w;          colbase = 0;   n_dst = I_NODES; }
    else           { offs = offs_u; srcs = sorted_iu; ex = ex_iu; dst = (bid - IBLK) * 4 + w; colbase = 512; n_dst = U_NODES; }
    if (dst >= n_dst) return;
    int h = lane >> 3;
    int j0 = offs[dst], j1 = offs[dst + 1];

    // single pass: accumulate unnormalized sum and denominator together.
    // all 8 lanes of head h load the same ex value -> den is free per lane.
    float den = 0.f;
    float acc[8] = {0.f, 0.f, 0.f, 0.f, 0.f, 0.f, 0.f, 0.f};
    const int fb = colbase + lane * 8;
    int j = j0;
    for (; j + 8 <= j1; j += 8) {
        int s[8]; float wt[8]; short8 f[8];
        #pragma unroll
        for (int i = 0; i < 8; ++i) s[i] = srcs[j + i];
        #pragma unroll
        for (int i = 0; i < 8; ++i) wt[i] = ex[(size_t)(j + i) * 8 + h];
        #pragma unroll
        for (int i = 0; i < 8; ++i) f[i] = *(const short8*)&F[(size_t)s[i] * 1024 + fb];
        #pragma unroll
        for (int i = 0; i < 8; ++i) {
            den += wt[i];
            #pragma unroll
            for (int q = 0; q < 8; ++q) acc[q] += wt[i] * b2f(f[i][q]);
        }
    }
    for (; j + 4 <= j1; j += 4) {
        int s[4]; float wt[4]; short8 f[4];
        #pragma unroll
        for (int i = 0; i < 4; ++i) s[i] = srcs[j + i];
        #pragma unroll
        for (int i = 0; i < 4; ++i) wt[i] = ex[(size_t)(j + i) * 8 + h];
        #pragma unroll
        for (int i = 0; i < 4; ++i) f[i] = *(const short8*)&F[(size_t)s[i] * 1024 + fb];
        #pragma unroll
        for (int i = 0; i < 4; ++i) {
            den += wt[i];
            #pragma unroll
            for (int q = 0; q < 8; ++q) acc[q] += wt[i] * b2f(f[i][q]);
        }
    }
    for (; j < j1; ++j) {
        int s0 = srcs[j];
        float w0 = ex[(size_t)j * 8 + h];
        short8 f0 = *(const short8*)&F[(size_t)s0 * 1024 + fb];
        den += w0;
        #pragma unroll
        for (int q = 0; q < 8; ++q) acc[q] += w0 * b2f(f0[q]);
    }
    float inv = (j1 > j0) ? (1.f / den) : 0.f;
    #pragma unroll
    for (int q = 0; q < 8; ++q) acc[q] *= inv;

    int col = lane * 8;
    if (item_mode) {
        float* o = itemF + (size_t)dst * 512 + col;       // bias folded in later
        float4 v0 = {acc[0], acc[1], acc[2], acc[3]};
        float4 v1 = {acc[4], acc[5], acc[6], acc[7]};
        *(float4*)(o + 0) = v0;
        *(float4*)(o + 4) = v1;
    } else {
        float* o = out + (size_t)dst * 1024 + col;
        float4 v0 = {acc[0] + b_iu[col + 0], acc[1] + b_iu[col + 1],
                     acc[2] + b_iu[col + 2], acc[3] + b_iu[col + 3]};
        float4 v1 = {acc[4] + b_iu[col + 4], acc[5] + b_iu[col + 5],
                     acc[6] + b_iu[col + 6], acc[7] + b_iu[col + 7]};
        *(float4*)(o + 0) = v0;
        *(float4*)(o + 4) = v1;
    }
}

// ---------------- item mean: tree reduce itemF[20000][512] ----------------
// 40 blocks x 500 rows; block writes 2 partial stripes (rows split by t>>7)
__global__ void item_reduce(const float* __restrict__ itemF, float* __restrict__ partial2)
{
    int b = blockIdx.x;             // 0..39
    int t = threadIdx.x;            // 256
    int cg = (t & 127) * 4;         // column group (float4)
    int rp = t >> 7;                // 0/1
    float4 s = {0.f, 0.f, 0.f, 0.f};
    int r0 = b * 500;
    for (int r = r0 + rp; r < r0 + 500; r += 2) {
        float4 v = *(const float4*)&itemF[(size_t)r * 512 + cg];
        s.x += v.x; s.y += v.y; s.z += v.z; s.w += v.w;
    }
    *(float4*)&partial2[(size_t)(b * 2 + rp) * 512 + cg] = s;
}

__global__ void meanvec_kernel(const float* __restrict__ partial2, const float* __restrict__ b_ui,
                               float* __restrict__ mean_vec)
{
    int c = threadIdx.x;   // 512
    float s = 0.f;
    for (int p = 0; p < 80; ++p) s += partial2[p * 512 + c];
    mean_vec[c] = s * (1.0f / (float)I_NODES) + b_ui[c];
}

__global__ void bcast_kernel(const float* __restrict__ mean_vec, float* __restrict__ out)
{
    int t = blockIdx.x * 256 + threadIdx.x;   // U*128
    int u = t >> 7, q = t & 127;
    float4 v = ((const float4*)mean_vec)[q];
    *(float4*)(out + (size_t)u * 1024 + 512 + q * 4) = v;
}

extern "C" void kernel_launch(void* const* d_in, const int* in_sizes, int n_in,
                              void* d_out, int out_size, void* d_ws, size_t ws_size,
                              hipStream_t stream)
{
    const int*   u_gid    = (const int*)d_in[0];
    const int*   i_gid    = (const int*)d_in[1];
    const int*   src_u    = (const int*)d_in[2];
    const int*   dst_i    = (const int*)d_in[3];
    const float* user_emb = (const float*)d_in[4];
    const float* item_emb = (const float*)d_in[5];
    const float* W_ui     = (const float*)d_in[6];
    const float* al_ui    = (const float*)d_in[7];
    const float* ar_ui    = (const float*)d_in[8];
    const float* b_ui     = (const float*)d_in[9];
    const float* W_iu     = (const float*)d_in[10];
    const float* al_iu    = (const float*)d_in[11];
    const float* ar_iu    = (const float*)d_in[12];
    const float* b_iu     = (const float*)d_in[13];
    float* out = (float*)d_out;

    char* ws = (char*)d_ws;
    size_t off = 0;
    auto alloc = [&](size_t bytes) -> void* {
        void* p = ws + off;
        off = (off + bytes + 255) & ~(size_t)255;
        return p;
    };
    uint16_t* Xb   = (uint16_t*)alloc((size_t)M_PAD * 512 * 2);
    uint16_t* Wt   = (uint16_t*)alloc((size_t)1024 * 512 * 2);
    uint16_t* F    = (uint16_t*)alloc((size_t)M_PAD * 1024 * 2);
    float* ELui    = (float*)alloc((size_t)N_NODES * 8 * 4);
    float* ERui    = (float*)alloc((size_t)N_NODES * 8 * 4);
    float* ELiu    = (float*)alloc((size_t)N_NODES * 8 * 4);
    float* ERiu    = (float*)alloc((size_t)N_NODES * 8 * 4);
    int* offs_i    = (int*)alloc((size_t)(I_NODES + 1) * 4);
    int* cur_i     = (int*)alloc((size_t)I_NODES * 4);
    int* offs_u    = (int*)alloc((size_t)(U_NODES + 1) * 4);
    int* cur_u     = (int*)alloc((size_t)U_NODES * 4);
    int* sorted_ui = (int*)alloc((size_t)E_EDGES * 4);
    int* sorted_iu = (int*)alloc((size_t)E_EDGES * 4);
    float* ex_ui   = (float*)alloc((size_t)E_EDGES * 8 * 4);
    float* ex_iu   = (float*)alloc((size_t)E_EDGES * 8 * 4);
    float* itemF   = (float*)alloc((size_t)I_NODES * 512 * 4);
    float* partial2= (float*)alloc((size_t)80 * 512 * 4);
    // zeroed region (contiguous): counts_i, counts_u
    char* zptr = ws + off;
    int*   counts_i = (int*)alloc((size_t)I_NODES * 4);
    int*   counts_u = (int*)alloc((size_t)U_NODES * 4);
    size_t zbytes = (size_t)((ws + off) - zptr);
    float* mean_vec = (float*)alloc(512 * 4);
    (void)ws_size; (void)in_sizes; (void)n_in; (void)out_size;

    hipMemsetAsync(zptr, 0, zbytes, stream);
    prep_w<<<2048, 256, 0, stream>>>(W_ui, W_iu, Wt);
    gather_cast<<<M_PAD * 128 / 256, 256, 0, stream>>>(u_gid, i_gid, user_emb, item_emb, Xb);
    gemm_bf16<<<(M_PAD / 128) * 8, 256, 0, stream>>>(Xb, Wt, F);
    elr_kernel<<<(N_NODES + 3) / 4, 256, 0, stream>>>(F, al_ui, ar_ui, al_iu, ar_iu,
                                                      ELui, ERui, ELiu, ERiu);
    hist_kernel<<<(E_EDGES + 255) / 256, 256, 0, stream>>>(src_u, dst_i, counts_i, counts_u);
    scan_kernel<<<2, 1024, 0, stream>>>(counts_i, counts_u, offs_i, cur_i, offs_u, cur_u);
    scatter_kernel<<<(E_EDGES + 255) / 256, 256, 0, stream>>>(src_u, dst_i, cur_i, cur_u,
                                                              sorted_ui, sorted_iu,
                                                              ELui, ERui, ELiu, ERiu,
                                                              ex_ui, ex_iu);
    agg3_kernel<<<IBLK + UBLK, 256, 0, stream>>>(offs_i, sorted_ui, ex_ui,
                                                 offs_u, sorted_iu, ex_iu,
                                                 F, b_iu, out, itemF);
    item_reduce<<<40, 256, 0, stream>>>(itemF, partial2);
    meanvec_kernel<<<1, 512, 0, stream>>>(partial2, b_ui, mean_vec);
    bcast_kernel<<<U_NODES * 128 / 256, 256, 0, stream>>>(mean_vec, out);
}